// Round 7
// baseline (206.254 us; speedup 1.0000x reference)
//
#include <hip/hip_runtime.h>
#include <hip/hip_bf16.h>

#define DIM   1024
#define NHEAD 16
#define HD    64
#define SEQ   2048
#define BATCH 2
#define QKV3  3072

using short8 = __attribute__((ext_vector_type(8))) short;
using f32x4  = __attribute__((ext_vector_type(4))) float;

// fp32 -> bf16 (RNE) scalar
__device__ inline short f2bf(float f) {
    union { float f; unsigned u; } x; x.f = f;
    const unsigned r = (x.u + 0x7FFFu + ((x.u >> 16) & 1u)) >> 16;
    return (short)r;
}
// packed 2x fp32 -> bf16x2 (v_cvt_pk_bf16_f32)
__device__ inline unsigned pkbf(float a, float b) {
    union { __hip_bfloat162 h; unsigned u; } cv;
    cv.h = __float22bfloat162_rn(make_float2(a, b));
    return cv.u;
}

// async global->LDS DMA, 16 B per lane, LDS dest = wave-uniform base + lane*16.
__device__ __forceinline__ void g2l16(const void* gptr, void* ldsbase) {
    __builtin_amdgcn_global_load_lds(
        (const __attribute__((address_space(1))) unsigned int*)(unsigned long long)gptr,
        (__attribute__((address_space(3))) unsigned int*)(unsigned int)(unsigned long long)ldsbase,
        16, 0, 0);
}

// ======================================================================
// Convert x, W_kqv, W_out to bf16 (one pass).
// ======================================================================
__global__ __launch_bounds__(256)
void conv_bf16(const float* __restrict__ x, const float* __restrict__ wk,
               const float* __restrict__ wo,
               unsigned short* __restrict__ xb, unsigned short* __restrict__ wkb,
               unsigned short* __restrict__ wob)
{
    const int bid = blockIdx.x;
    const float* src; unsigned short* dst; size_t base;
    if (bid < 1024)      { src = x;  dst = xb;  base = (size_t)bid * 4096; }
    else if (bid < 1792) { src = wk; dst = wkb; base = (size_t)(bid - 1024) * 4096; }
    else                 { src = wo; dst = wob; base = (size_t)(bid - 1792) * 4096; }
    const size_t off = base + threadIdx.x * 16;
    const float4 f0 = *(const float4*)(src + off + 0);
    const float4 f1 = *(const float4*)(src + off + 4);
    const float4 f2 = *(const float4*)(src + off + 8);
    const float4 f3 = *(const float4*)(src + off + 12);
    uint4 o0, o1;
    o0.x = pkbf(f0.x, f0.y); o0.y = pkbf(f0.z, f0.w);
    o0.z = pkbf(f1.x, f1.y); o0.w = pkbf(f1.z, f1.w);
    o1.x = pkbf(f2.x, f2.y); o1.y = pkbf(f2.z, f2.w);
    o1.z = pkbf(f3.x, f3.y); o1.w = pkbf(f3.z, f3.w);
    *(uint4*)(dst + off + 0) = o0;
    *(uint4*)(dst + off + 8) = o1;
}

// ======================================================================
// QKV GEMM (unchanged from round 6): pure bf16, global_load_lds staging,
// XOR-swizzled unpadded LDS. Epilogue: q (x0.125), k -> [b,h,s,d];
// v -> transposed [b,h,d,s].
// ======================================================================
__global__ __launch_bounds__(256)
void gemm_qkv(const unsigned short* __restrict__ A, const unsigned short* __restrict__ B,
              const float* __restrict__ bias,
              unsigned short* __restrict__ qbf, unsigned short* __restrict__ kbf,
              unsigned short* __restrict__ vtbf)
{
    constexpr int BK = 32;
    const int K = DIM;
    __shared__ short As[128 * BK];
    __shared__ short Bs[128 * BK];

    const int tid  = threadIdx.x;
    const int lane = tid & 63;
    const int wave = tid >> 6;
    const int quad = lane >> 4;
    const int ln   = lane & 15;
    const int wm   = (wave & 1) * 64;
    const int wn   = (wave >> 1) * 64;

    const int bid = blockIdx.x;
    const int xcd = bid & 7;
    const int t   = bid >> 3;
    const int m0  = (xcd * 4 + (t & 3)) * 128;
    const int n0  = (t >> 2) * 128;

    int srow[2], sg[2];
#pragma unroll
    for (int i = 0; i < 2; ++i) {
        const int c  = wave * 128 + i * 64 + lane;
        srow[i] = c >> 2;
        sg[i]   = (c & 3) ^ ((srow[i] >> 1) & 3);
    }

    f32x4 acc[4][4];
#pragma unroll
    for (int i = 0; i < 4; ++i)
#pragma unroll
        for (int j = 0; j < 4; ++j) acc[i][j] = (f32x4){0.f, 0.f, 0.f, 0.f};

    for (int k0 = 0; k0 < K; k0 += BK) {
        __syncthreads();
#pragma unroll
        for (int i = 0; i < 2; ++i) {
            const int cb = wave * 128 + i * 64;
            g2l16(A + (size_t)(m0 + srow[i]) * K + k0 + sg[i] * 8, &As[cb * 8]);
            g2l16(B + (size_t)(n0 + srow[i]) * K + k0 + sg[i] * 8, &Bs[cb * 8]);
        }
        __syncthreads();

        short8 a[4], b[4];
#pragma unroll
        for (int i = 0; i < 4; ++i) {
            const int row = wm + i * 16 + ln;
            const int ch  = quad ^ ((row >> 1) & 3);
            a[i] = *(const short8*)&As[row * BK + ch * 8];
        }
#pragma unroll
        for (int j = 0; j < 4; ++j) {
            const int row = wn + j * 16 + ln;
            const int ch  = quad ^ ((row >> 1) & 3);
            b[j] = *(const short8*)&Bs[row * BK + ch * 8];
        }
#pragma unroll
        for (int i = 0; i < 4; ++i)
#pragma unroll
            for (int j = 0; j < 4; ++j)
                acc[i][j] = __builtin_amdgcn_mfma_f32_16x16x32_bf16(
                    a[i], b[j], acc[i][j], 0, 0, 0);
    }

#pragma unroll
    for (int j = 0; j < 4; ++j) {
        const int col = n0 + wn + j * 16 + ln;
        const int sel = col >> 10;
        const int c   = col & 1023;
        const int hh  = c >> 6;
        const int dd  = c & 63;
        const float bv = bias[col];
        if (sel < 2) {
            unsigned short* dst = (sel == 0) ? qbf : kbf;
            const float qs = (sel == 0) ? 0.125f : 1.0f;
#pragma unroll
            for (int i = 0; i < 4; ++i)
#pragma unroll
                for (int r2 = 0; r2 < 4; ++r2) {
                    const int row = m0 + wm + i * 16 + quad * 4 + r2;
                    const int bb = row >> 11, ss = row & 2047;
                    dst[((size_t)(bb * NHEAD + hh) * SEQ + ss) * HD + dd] =
                        (unsigned short)f2bf((acc[i][j][r2] + bv) * qs);
                }
        } else {
            const int row0 = m0 + wm + quad * 4;
            const int bb = row0 >> 11;
            const size_t vbase = ((size_t)(bb * NHEAD + hh) * HD + dd) * SEQ;
#pragma unroll
            for (int i = 0; i < 4; ++i) {
                const int ss0 = (row0 & 2047) + i * 16;
                uint2 pk;
                pk.x = pkbf(acc[i][j][0] + bv, acc[i][j][1] + bv);
                pk.y = pkbf(acc[i][j][2] + bv, acc[i][j][3] + bv);
                *(uint2*)&vtbf[vbase + ss0] = pk;
            }
        }
    }
}

// ======================================================================
// Flash attention, bf16 MFMA, no-max softmax. BQ=64: block = (b,h,qt),
// 4 waves, wave = 16 q-rows. 1024 blocks -> 4/CU (2x round 6 TLP).
// bid = qt*32 + bh so bid&7 = bh&7 -> same-head blocks land on one XCD
// (KV stays L2-resident, 4 heads x 512 KB = 2 MB per XCD).
// l computed as P @ ones via 2 extra MFMA/iter (B-frag = bf16 1.0,
// no LDS read) -> kills the VALU lsum adds and the end-of-kernel
// shuffle+LDS transpose; l exits C-layout-aligned with O.
// ======================================================================
__global__ __launch_bounds__(256)
void attn_flash_mfma(const unsigned short* __restrict__ qbf,
                     const unsigned short* __restrict__ kbf,
                     const unsigned short* __restrict__ vtbf,
                     unsigned short* __restrict__ ctxbf)
{
    constexpr int LDK = 72, LDV = 72, LDP = 72;
    __shared__ short Ks[64 * LDK];   // K tile [key][d]
    __shared__ short Vt[64 * LDV];   // V^T tile [d][key]
    __shared__ short Ps[64 * LDP];   // Q stage, then P [q][key] (wave-private)

    const int tid  = threadIdx.x;
    const int lane = tid & 63;
    const int wave = tid >> 6;
    const int quad = lane >> 4;
    const int ln   = lane & 15;

    const int bid = blockIdx.x;          // qt*32 + bh
    const int bh  = bid & 31;            // b*16+h; low 3 bits pick XCD
    const int qt  = bid >> 5;            // 0..31
    const int q0  = qt * 64;
    const int b   = bh >> 4;
    const int h   = bh & 15;

    const size_t sbase = (size_t)bh * SEQ * HD;
    const size_t vbase = (size_t)bh * HD * SEQ;

    // ---- stage Q (64x64) into Ps, read frags
#pragma unroll
    for (int it = 0; it < 2; ++it) {
        const int ch = tid + it * 256;   // 0..511
        const int r  = ch >> 3;
        const int cc = ch & 7;
        *(short8*)&Ps[r * LDP + cc * 8] =
            *(const short8*)&qbf[sbase + (size_t)(q0 + r) * HD + cc * 8];
    }
    __syncthreads();
    short8 qf[2];
    qf[0] = *(const short8*)&Ps[(wave * 16 + ln) * LDP + quad * 8];
    qf[1] = *(const short8*)&Ps[(wave * 16 + ln) * LDP + 32 + quad * 8];

    f32x4 O[4];
#pragma unroll
    for (int dj = 0; dj < 4; ++dj) O[dj] = (f32x4){0.f, 0.f, 0.f, 0.f};
    f32x4 lacc = (f32x4){0.f, 0.f, 0.f, 0.f};

    short8 vone;
#pragma unroll
    for (int t = 0; t < 8; ++t) vone[t] = (short)0x3F80;   // bf16 1.0

    // ---- prefetch tile 0
    short8 kr[2], vr[2];
#pragma unroll
    for (int it = 0; it < 2; ++it) {
        const int ch = tid + it * 256;
        const int r  = ch >> 3;
        const int cc = ch & 7;
        kr[it] = *(const short8*)&kbf[sbase + (size_t)r * HD + cc * 8];
        vr[it] = *(const short8*)&vtbf[vbase + (size_t)r * SEQ + cc * 8];
    }

    for (int kt = 0; kt < SEQ / 64; ++kt) {
        __syncthreads();
#pragma unroll
        for (int it = 0; it < 2; ++it) {
            const int ch = tid + it * 256;
            const int r  = ch >> 3;
            const int cc = ch & 7;
            *(short8*)&Ks[r * LDK + cc * 8] = kr[it];
            *(short8*)&Vt[r * LDV + cc * 8] = vr[it];
        }
        if (kt + 1 < SEQ / 64) {
            const int k0n = (kt + 1) * 64;
#pragma unroll
            for (int it = 0; it < 2; ++it) {
                const int ch = tid + it * 256;
                const int r  = ch >> 3;
                const int cc = ch & 7;
                kr[it] = *(const short8*)&kbf[sbase + (size_t)(k0n + r) * HD + cc * 8];
                vr[it] = *(const short8*)&vtbf[vbase + (size_t)r * SEQ + k0n + cc * 8];
            }
        }
        __syncthreads();

        // ---- S^T = K Q^T : col=q(ln), row=key(quad*4+r2), 4 key-16 tiles
        f32x4 st[4];
#pragma unroll
        for (int j = 0; j < 4; ++j) {
            const short8 kf0 = *(const short8*)&Ks[(j * 16 + ln) * LDK + quad * 8];
            const short8 kf1 = *(const short8*)&Ks[(j * 16 + ln) * LDK + 32 + quad * 8];
            f32x4 tt = __builtin_amdgcn_mfma_f32_16x16x32_bf16(
                kf0, qf[0], (f32x4){0.f, 0.f, 0.f, 0.f}, 0, 0, 0);
            st[j] = __builtin_amdgcn_mfma_f32_16x16x32_bf16(kf1, qf[1], tt, 0, 0, 0);
        }

        // ---- P = exp(S), pack bf16 into A-layout Ps (wave-private rows)
#pragma unroll
        for (int j = 0; j < 4; ++j) {
            const float p0 = __expf(st[j][0]);
            const float p1 = __expf(st[j][1]);
            const float p2 = __expf(st[j][2]);
            const float p3 = __expf(st[j][3]);
            uint2 pk;
            pk.x = pkbf(p0, p1);
            pk.y = pkbf(p2, p3);
            *(uint2*)&Ps[(wave * 16 + ln) * LDP + j * 16 + quad * 4] = pk;
        }

        // ---- O += P @ V ; l += P @ 1 (MFMA, no LDS read for ones)
#pragma unroll
        for (int kc = 0; kc < 2; ++kc) {
            const short8 pf = *(const short8*)&Ps[(wave * 16 + ln) * LDP + kc * 32 + quad * 8];
            lacc = __builtin_amdgcn_mfma_f32_16x16x32_bf16(pf, vone, lacc, 0, 0, 0);
#pragma unroll
            for (int dj = 0; dj < 4; ++dj) {
                const short8 vf = *(const short8*)&Vt[(dj * 16 + ln) * LDV + kc * 32 + quad * 8];
                O[dj] = __builtin_amdgcn_mfma_f32_16x16x32_bf16(pf, vf, O[dj], 0, 0, 0);
            }
        }
    }

    // ---- epilogue: l is C-layout-aligned with O (row = quad*4+r2)
#pragma unroll
    for (int r2 = 0; r2 < 4; ++r2) {
        const float inv = 1.0f / lacc[r2];
        const int row = b * SEQ + q0 + wave * 16 + quad * 4 + r2;
#pragma unroll
        for (int dj = 0; dj < 4; ++dj)
            ctxbf[(size_t)row * DIM + h * HD + dj * 16 + ln] =
                (unsigned short)f2bf(O[dj][r2] * inv);
    }
}

// ======================================================================
// Out-proj GEMM (unchanged from round 6).
// ======================================================================
__global__ __launch_bounds__(256)
void gemm_out(const unsigned short* __restrict__ A, const unsigned short* __restrict__ B,
              const float* __restrict__ bias, float* __restrict__ C)
{
    constexpr int BK = 32;
    const int K = DIM, N = DIM;
    __shared__ short As[128 * BK];
    __shared__ short Bs[64 * BK];

    const int tid  = threadIdx.x;
    const int lane = tid & 63;
    const int wave = tid >> 6;
    const int quad = lane >> 4;
    const int ln   = lane & 15;
    const int wm   = (wave & 1) * 64;
    const int wn   = (wave >> 1) * 32;

    const int bid = blockIdx.x;
    const int xcd = bid & 7;
    const int t   = bid >> 3;
    const int m0  = (xcd * 4 + (t & 3)) * 128;
    const int n0  = (t >> 2) * 64;

    int srow[2], sg[2];
#pragma unroll
    for (int i = 0; i < 2; ++i) {
        const int c  = wave * 128 + i * 64 + lane;
        srow[i] = c >> 2;
        sg[i]   = (c & 3) ^ ((srow[i] >> 1) & 3);
    }
    const int cB  = wave * 64 + lane;
    const int brow = cB >> 2;
    const int bg   = (cB & 3) ^ ((brow >> 1) & 3);

    f32x4 acc[4][2];
#pragma unroll
    for (int i = 0; i < 4; ++i)
#pragma unroll
        for (int j = 0; j < 2; ++j) acc[i][j] = (f32x4){0.f, 0.f, 0.f, 0.f};

    for (int k0 = 0; k0 < K; k0 += BK) {
        __syncthreads();
#pragma unroll
        for (int i = 0; i < 2; ++i)
            g2l16(A + (size_t)(m0 + srow[i]) * K + k0 + sg[i] * 8,
                  &As[(wave * 128 + i * 64) * 8]);
        g2l16(B + (size_t)(n0 + brow) * K + k0 + bg * 8, &Bs[(wave * 64) * 8]);
        __syncthreads();

        short8 a[4], b[2];
#pragma unroll
        for (int i = 0; i < 4; ++i) {
            const int row = wm + i * 16 + ln;
            const int ch  = quad ^ ((row >> 1) & 3);
            a[i] = *(const short8*)&As[row * BK + ch * 8];
        }
#pragma unroll
        for (int j = 0; j < 2; ++j) {
            const int row = wn + j * 16 + ln;
            const int ch  = quad ^ ((row >> 1) & 3);
            b[j] = *(const short8*)&Bs[row * BK + ch * 8];
        }
#pragma unroll
        for (int i = 0; i < 4; ++i)
#pragma unroll
            for (int j = 0; j < 2; ++j)
                acc[i][j] = __builtin_amdgcn_mfma_f32_16x16x32_bf16(
                    a[i], b[j], acc[i][j], 0, 0, 0);
    }

#pragma unroll
    for (int j = 0; j < 2; ++j) {
        const int col = n0 + wn + j * 16 + ln;
        const float bv = bias[col];
#pragma unroll
        for (int i = 0; i < 4; ++i)
#pragma unroll
            for (int r2 = 0; r2 < 4; ++r2) {
                const int row = m0 + wm + i * 16 + quad * 4 + r2;
                C[(size_t)row * N + col] = acc[i][j][r2] + bv;
            }
    }
}

extern "C" void kernel_launch(void* const* d_in, const int* in_sizes, int n_in,
                              void* d_out, int out_size, void* d_ws, size_t ws_size,
                              hipStream_t stream)
{
    const float* x     = (const float*)d_in[0];
    const float* W_kqv = (const float*)d_in[1];
    const float* b_kqv = (const float*)d_in[2];
    const float* W_out = (const float*)d_in[3];
    const float* b_out = (const float*)d_in[4];
    float* out = (float*)d_out;

    char* w = (char*)d_ws;
    unsigned short* qbf   = (unsigned short*)w;  w += (size_t)BATCH * NHEAD * SEQ * HD * 2;
    unsigned short* kbf   = (unsigned short*)w;  w += (size_t)BATCH * NHEAD * SEQ * HD * 2;
    unsigned short* vtbf  = (unsigned short*)w;  w += (size_t)BATCH * NHEAD * HD * SEQ * 2;
    unsigned short* ctxbf = (unsigned short*)w;  w += (size_t)BATCH * SEQ * DIM * 2;
    unsigned short* xb    = (unsigned short*)w;  w += (size_t)BATCH * SEQ * DIM * 2;
    unsigned short* wkb   = (unsigned short*)w;  w += (size_t)QKV3 * DIM * 2;
    unsigned short* wob   = (unsigned short*)w;

    dim3 blk(256);

    conv_bf16<<<dim3(2048), blk, 0, stream>>>(x, W_kqv, W_out, xb, wkb, wob);

    gemm_qkv<<<dim3(768), blk, 0, stream>>>(xb, wkb, b_kqv, qbf, kbf, vtbf);

    // 1024 blocks: bid = qt*32 + bh (bh in low bits -> XCD-local KV)
    attn_flash_mfma<<<dim3(1024), blk, 0, stream>>>(qbf, kbf, vtbf, ctxbf);

    gemm_out<<<dim3(512), blk, 0, stream>>>(ctxbf, wob, b_out, out);
}

// Round 8
// 205.280 us; speedup vs baseline: 1.0047x; 1.0047x over previous
//
#include <hip/hip_runtime.h>
#include <hip/hip_bf16.h>

#define DIM   1024
#define NHEAD 16
#define HD    64
#define SEQ   2048
#define BATCH 2
#define QKV3  3072

using short8 = __attribute__((ext_vector_type(8))) short;
using f32x4  = __attribute__((ext_vector_type(4))) float;

// fp32 -> bf16 (RNE) scalar
__device__ inline short f2bf(float f) {
    union { float f; unsigned u; } x; x.f = f;
    const unsigned r = (x.u + 0x7FFFu + ((x.u >> 16) & 1u)) >> 16;
    return (short)r;
}
// packed 2x fp32 -> bf16x2 (v_cvt_pk_bf16_f32)
__device__ inline unsigned pkbf(float a, float b) {
    union { __hip_bfloat162 h; unsigned u; } cv;
    cv.h = __float22bfloat162_rn(make_float2(a, b));
    return cv.u;
}

// async global->LDS DMA, 16 B per lane, LDS dest = wave-uniform base + lane*16.
__device__ __forceinline__ void g2l16(const void* gptr, void* ldsbase) {
    __builtin_amdgcn_global_load_lds(
        (const __attribute__((address_space(1))) unsigned int*)(unsigned long long)gptr,
        (__attribute__((address_space(3))) unsigned int*)(unsigned int)(unsigned long long)ldsbase,
        16, 0, 0);
}

// ======================================================================
// Convert x, W_kqv, W_out to bf16 (one pass).
// ======================================================================
__global__ __launch_bounds__(256)
void conv_bf16(const float* __restrict__ x, const float* __restrict__ wk,
               const float* __restrict__ wo,
               unsigned short* __restrict__ xb, unsigned short* __restrict__ wkb,
               unsigned short* __restrict__ wob)
{
    const int bid = blockIdx.x;
    const float* src; unsigned short* dst; size_t base;
    if (bid < 1024)      { src = x;  dst = xb;  base = (size_t)bid * 4096; }
    else if (bid < 1792) { src = wk; dst = wkb; base = (size_t)(bid - 1024) * 4096; }
    else                 { src = wo; dst = wob; base = (size_t)(bid - 1792) * 4096; }
    const size_t off = base + threadIdx.x * 16;
    const float4 f0 = *(const float4*)(src + off + 0);
    const float4 f1 = *(const float4*)(src + off + 4);
    const float4 f2 = *(const float4*)(src + off + 8);
    const float4 f3 = *(const float4*)(src + off + 12);
    uint4 o0, o1;
    o0.x = pkbf(f0.x, f0.y); o0.y = pkbf(f0.z, f0.w);
    o0.z = pkbf(f1.x, f1.y); o0.w = pkbf(f1.z, f1.w);
    o1.x = pkbf(f2.x, f2.y); o1.y = pkbf(f2.z, f2.w);
    o1.z = pkbf(f3.x, f3.y); o1.w = pkbf(f3.z, f3.w);
    *(uint4*)(dst + off + 0) = o0;
    *(uint4*)(dst + off + 8) = o1;
}

// ======================================================================
// QKV GEMM (round-6 structure). Epilogue: q scaled by 0.125*log2(e) so
// attention softmax uses a bare exp2 (one v_exp_f32, no pre-mul).
// ======================================================================
__global__ __launch_bounds__(256)
void gemm_qkv(const unsigned short* __restrict__ A, const unsigned short* __restrict__ B,
              const float* __restrict__ bias,
              unsigned short* __restrict__ qbf, unsigned short* __restrict__ kbf,
              unsigned short* __restrict__ vtbf)
{
    constexpr int BK = 32;
    const int K = DIM;
    __shared__ short As[128 * BK];
    __shared__ short Bs[128 * BK];

    const int tid  = threadIdx.x;
    const int lane = tid & 63;
    const int wave = tid >> 6;
    const int quad = lane >> 4;
    const int ln   = lane & 15;
    const int wm   = (wave & 1) * 64;
    const int wn   = (wave >> 1) * 64;

    const int bid = blockIdx.x;
    const int xcd = bid & 7;
    const int t   = bid >> 3;
    const int m0  = (xcd * 4 + (t & 3)) * 128;
    const int n0  = (t >> 2) * 128;

    int srow[2], sg[2];
#pragma unroll
    for (int i = 0; i < 2; ++i) {
        const int c  = wave * 128 + i * 64 + lane;
        srow[i] = c >> 2;
        sg[i]   = (c & 3) ^ ((srow[i] >> 1) & 3);
    }

    f32x4 acc[4][4];
#pragma unroll
    for (int i = 0; i < 4; ++i)
#pragma unroll
        for (int j = 0; j < 4; ++j) acc[i][j] = (f32x4){0.f, 0.f, 0.f, 0.f};

    for (int k0 = 0; k0 < K; k0 += BK) {
        __syncthreads();
#pragma unroll
        for (int i = 0; i < 2; ++i) {
            const int cb = wave * 128 + i * 64;
            g2l16(A + (size_t)(m0 + srow[i]) * K + k0 + sg[i] * 8, &As[cb * 8]);
            g2l16(B + (size_t)(n0 + srow[i]) * K + k0 + sg[i] * 8, &Bs[cb * 8]);
        }
        __syncthreads();

        short8 a[4], b[4];
#pragma unroll
        for (int i = 0; i < 4; ++i) {
            const int row = wm + i * 16 + ln;
            const int ch  = quad ^ ((row >> 1) & 3);
            a[i] = *(const short8*)&As[row * BK + ch * 8];
        }
#pragma unroll
        for (int j = 0; j < 4; ++j) {
            const int row = wn + j * 16 + ln;
            const int ch  = quad ^ ((row >> 1) & 3);
            b[j] = *(const short8*)&Bs[row * BK + ch * 8];
        }
#pragma unroll
        for (int i = 0; i < 4; ++i)
#pragma unroll
            for (int j = 0; j < 4; ++j)
                acc[i][j] = __builtin_amdgcn_mfma_f32_16x16x32_bf16(
                    a[i], b[j], acc[i][j], 0, 0, 0);
    }

#pragma unroll
    for (int j = 0; j < 4; ++j) {
        const int col = n0 + wn + j * 16 + ln;
        const int sel = col >> 10;
        const int c   = col & 1023;
        const int hh  = c >> 6;
        const int dd  = c & 63;
        const float bv = bias[col];
        if (sel < 2) {
            unsigned short* dst = (sel == 0) ? qbf : kbf;
            // 0.125 * log2(e): softmax becomes exp2 of the raw score
            const float qs = (sel == 0) ? 0.18033688f : 1.0f;
#pragma unroll
            for (int i = 0; i < 4; ++i)
#pragma unroll
                for (int r2 = 0; r2 < 4; ++r2) {
                    const int row = m0 + wm + i * 16 + quad * 4 + r2;
                    const int bb = row >> 11, ss = row & 2047;
                    dst[((size_t)(bb * NHEAD + hh) * SEQ + ss) * HD + dd] =
                        (unsigned short)f2bf((acc[i][j][r2] + bv) * qs);
                }
        } else {
            const int row0 = m0 + wm + quad * 4;
            const int bb = row0 >> 11;
            const size_t vbase = ((size_t)(bb * NHEAD + hh) * HD + dd) * SEQ;
#pragma unroll
            for (int i = 0; i < 4; ++i) {
                const int ss0 = (row0 & 2047) + i * 16;
                uint2 pk;
                pk.x = pkbf(acc[i][j][0] + bv, acc[i][j][1] + bv);
                pk.y = pkbf(acc[i][j][2] + bv, acc[i][j][3] + bv);
                *(uint2*)&vtbf[vbase + ss0] = pk;
            }
        }
    }
}

// ======================================================================
// Flash attention, bf16 MFMA, no-max softmax (exp2; log2e pre-folded
// into Q). BQ=128 (4 waves x 32 q-rows), BKT=64, 512 blocks.
// bid = qt*32 + bh -> bid&7 = h&7: same-head blocks share an XCD, KV
// stays L2-resident (measured r7: FETCH 69.7 -> 12.3 MB).
// K/V staged by global_load_lds DMA into PING-PONG buffers: DMA for
// tile kt+1 issued at top of iter kt into the idle buffer; the single
// end-of-iter barrier (vmcnt drain) covers it -> 1 barrier/iter, no
// staging VALU, no staging regs. Dense LDS rows (DMA) with the XOR
// chunk-swizzle folded into the DMA *source* address -> fragment b128
// reads are 2-way (free). l accumulated as P @ ones via MFMA.
// LDS ~50 KB -> 3 blocks/CU.
// ======================================================================
__global__ __launch_bounds__(256)
void attn_flash_mfma(const unsigned short* __restrict__ qbf,
                     const unsigned short* __restrict__ kbf,
                     const unsigned short* __restrict__ vtbf,
                     unsigned short* __restrict__ ctxbf)
{
    constexpr int LDP = 72;
    __shared__ short Ks[2][64 * 64];   // [key][d] dense, XOR-swizzled chunks
    __shared__ short Vt[2][64 * 64];   // [d][key] dense, XOR-swizzled chunks
    __shared__ short Ps[128 * LDP];    // Q stage, then P [q][key] (wave-private)

    const int tid  = threadIdx.x;
    const int lane = tid & 63;
    const int wave = tid >> 6;
    const int quad = lane >> 4;
    const int ln   = lane & 15;

    const int bid = blockIdx.x;          // qt*32 + bh
    const int bh  = bid & 31;
    const int qt  = bid >> 5;            // 0..15
    const int q0  = qt * 128;
    const int b   = bh >> 4;
    const int h   = bh & 15;

    const size_t sbase = (size_t)bh * SEQ * HD;
    const size_t vbase = (size_t)bh * HD * SEQ;

    // DMA staging geometry: tile = 64 rows x 8 chunks (16 B). Chunk ch for
    // this thread (2 per matrix): row r = ch>>3, slot cc = ch&7, source
    // chunk cg = cc ^ (r&7)  (swizzle folded into the global address).
    int srw[2], scg[2];
#pragma unroll
    for (int it = 0; it < 2; ++it) {
        const int ch = tid + it * 256;
        srw[it] = ch >> 3;
        scg[it] = (ch & 7) ^ (srw[it] & 7);
    }

    // ---- stage Q (128x64) into Ps
#pragma unroll
    for (int it = 0; it < 4; ++it) {
        const int ch = tid + it * 256;
        const int r  = ch >> 3;
        const int cc = ch & 7;
        *(short8*)&Ps[r * LDP + cc * 8] =
            *(const short8*)&qbf[sbase + (size_t)(q0 + r) * HD + cc * 8];
    }
    // ---- DMA tile 0 into buffer 0
#pragma unroll
    for (int it = 0; it < 2; ++it) {
        const int cb = tid + it * 256;   // linear chunk = LDS slot
        g2l16(kbf + sbase + (size_t)srw[it] * HD + scg[it] * 8, &Ks[0][cb * 8]);
        g2l16(vtbf + vbase + (size_t)srw[it] * SEQ + scg[it] * 8, &Vt[0][cb * 8]);
    }
    __syncthreads();   // Q staged + DMA drained

    short8 qf[2][2];
#pragma unroll
    for (int sm = 0; sm < 2; ++sm)
#pragma unroll
        for (int kc = 0; kc < 2; ++kc)
            qf[sm][kc] = *(const short8*)&Ps[(wave * 32 + sm * 16 + ln) * LDP + kc * 32 + quad * 8];

    f32x4 O[2][4];
#pragma unroll
    for (int sm = 0; sm < 2; ++sm)
#pragma unroll
        for (int dj = 0; dj < 4; ++dj) O[sm][dj] = (f32x4){0.f, 0.f, 0.f, 0.f};
    f32x4 lacc[2];
    lacc[0] = (f32x4){0.f, 0.f, 0.f, 0.f};
    lacc[1] = (f32x4){0.f, 0.f, 0.f, 0.f};

    short8 vone;
#pragma unroll
    for (int t = 0; t < 8; ++t) vone[t] = (short)0x3F80;   // bf16 1.0

    for (int kt = 0; kt < SEQ / 64; ++kt) {
        const int p = kt & 1;
        // issue DMA for tile kt+1 into the idle buffer (reads of it
        // completed before the previous barrier)
        if (kt + 1 < SEQ / 64) {
            const int k0n = (kt + 1) * 64;
#pragma unroll
            for (int it = 0; it < 2; ++it) {
                const int cb = tid + it * 256;
                g2l16(kbf + sbase + (size_t)(k0n + srw[it]) * HD + scg[it] * 8,
                      &Ks[1 - p][cb * 8]);
                g2l16(vtbf + vbase + (size_t)srw[it] * SEQ + k0n + scg[it] * 8,
                      &Vt[1 - p][cb * 8]);
            }
        }

        // ---- S^T = K Q^T : col=q(ln), row=key(quad*4+r2), 4 key-16 tiles
        f32x4 st[2][4];
#pragma unroll
        for (int j = 0; j < 4; ++j) {
            const int row = j * 16 + ln;
            const int c0 = quad ^ (row & 7);        // k-chunk quad
            const int c1 = (4 + quad) ^ (row & 7);  // k-chunk 4+quad
            const short8 kf0 = *(const short8*)&Ks[p][row * 64 + c0 * 8];
            const short8 kf1 = *(const short8*)&Ks[p][row * 64 + c1 * 8];
#pragma unroll
            for (int sm = 0; sm < 2; ++sm) {
                f32x4 tt = __builtin_amdgcn_mfma_f32_16x16x32_bf16(
                    kf0, qf[sm][0], (f32x4){0.f, 0.f, 0.f, 0.f}, 0, 0, 0);
                st[sm][j] = __builtin_amdgcn_mfma_f32_16x16x32_bf16(
                    kf1, qf[sm][1], tt, 0, 0, 0);
            }
        }

        // ---- P = exp2(S') (log2e folded into Q), pack bf16 -> Ps
#pragma unroll
        for (int sm = 0; sm < 2; ++sm)
#pragma unroll
            for (int j = 0; j < 4; ++j) {
                const float p0 = __builtin_amdgcn_exp2f(st[sm][j][0]);
                const float p1 = __builtin_amdgcn_exp2f(st[sm][j][1]);
                const float p2 = __builtin_amdgcn_exp2f(st[sm][j][2]);
                const float p3 = __builtin_amdgcn_exp2f(st[sm][j][3]);
                uint2 pk;
                pk.x = pkbf(p0, p1);
                pk.y = pkbf(p2, p3);
                *(uint2*)&Ps[(wave * 32 + sm * 16 + ln) * LDP + j * 16 + quad * 4] = pk;
            }

        // ---- O += P @ V ; l += P @ 1 (wave-private Ps rows, no barrier)
#pragma unroll
        for (int kc = 0; kc < 2; ++kc) {
            const short8 pf0 = *(const short8*)&Ps[(wave * 32 + ln) * LDP + kc * 32 + quad * 8];
            const short8 pf1 = *(const short8*)&Ps[(wave * 32 + 16 + ln) * LDP + kc * 32 + quad * 8];
            lacc[0] = __builtin_amdgcn_mfma_f32_16x16x32_bf16(pf0, vone, lacc[0], 0, 0, 0);
            lacc[1] = __builtin_amdgcn_mfma_f32_16x16x32_bf16(pf1, vone, lacc[1], 0, 0, 0);
#pragma unroll
            for (int dj = 0; dj < 4; ++dj) {
                const int row = dj * 16 + ln;
                const int cg  = (kc * 4 + quad) ^ (row & 7);
                const short8 vf = *(const short8*)&Vt[p][row * 64 + cg * 8];
                O[0][dj] = __builtin_amdgcn_mfma_f32_16x16x32_bf16(pf0, vf, O[0][dj], 0, 0, 0);
                O[1][dj] = __builtin_amdgcn_mfma_f32_16x16x32_bf16(pf1, vf, O[1][dj], 0, 0, 0);
            }
        }
        __syncthreads();   // single barrier: drains DMA, orders buffer reuse
    }

    // ---- epilogue: l (C-layout, aligned with O rows)
#pragma unroll
    for (int sm = 0; sm < 2; ++sm)
#pragma unroll
        for (int r2 = 0; r2 < 4; ++r2) {
            const float inv = 1.0f / lacc[sm][r2];
            const int row = b * SEQ + q0 + wave * 32 + sm * 16 + quad * 4 + r2;
#pragma unroll
            for (int dj = 0; dj < 4; ++dj)
                ctxbf[(size_t)row * DIM + h * HD + dj * 16 + ln] =
                    (unsigned short)f2bf(O[sm][dj][r2] * inv);
        }
}

// ======================================================================
// Out-proj GEMM (unchanged from round 6).
// ======================================================================
__global__ __launch_bounds__(256)
void gemm_out(const unsigned short* __restrict__ A, const unsigned short* __restrict__ B,
              const float* __restrict__ bias, float* __restrict__ C)
{
    constexpr int BK = 32;
    const int K = DIM, N = DIM;
    __shared__ short As[128 * BK];
    __shared__ short Bs[64 * BK];

    const int tid  = threadIdx.x;
    const int lane = tid & 63;
    const int wave = tid >> 6;
    const int quad = lane >> 4;
    const int ln   = lane & 15;
    const int wm   = (wave & 1) * 64;
    const int wn   = (wave >> 1) * 32;

    const int bid = blockIdx.x;
    const int xcd = bid & 7;
    const int t   = bid >> 3;
    const int m0  = (xcd * 4 + (t & 3)) * 128;
    const int n0  = (t >> 2) * 64;

    int srow[2], sg[2];
#pragma unroll
    for (int i = 0; i < 2; ++i) {
        const int c  = wave * 128 + i * 64 + lane;
        srow[i] = c >> 2;
        sg[i]   = (c & 3) ^ ((srow[i] >> 1) & 3);
    }
    const int cB  = wave * 64 + lane;
    const int brow = cB >> 2;
    const int bg   = (cB & 3) ^ ((brow >> 1) & 3);

    f32x4 acc[4][2];
#pragma unroll
    for (int i = 0; i < 4; ++i)
#pragma unroll
        for (int j = 0; j < 2; ++j) acc[i][j] = (f32x4){0.f, 0.f, 0.f, 0.f};

    for (int k0 = 0; k0 < K; k0 += BK) {
        __syncthreads();
#pragma unroll
        for (int i = 0; i < 2; ++i)
            g2l16(A + (size_t)(m0 + srow[i]) * K + k0 + sg[i] * 8,
                  &As[(wave * 128 + i * 64) * 8]);
        g2l16(B + (size_t)(n0 + brow) * K + k0 + bg * 8, &Bs[(wave * 64) * 8]);
        __syncthreads();

        short8 a[4], b[2];
#pragma unroll
        for (int i = 0; i < 4; ++i) {
            const int row = wm + i * 16 + ln;
            const int ch  = quad ^ ((row >> 1) & 3);
            a[i] = *(const short8*)&As[row * BK + ch * 8];
        }
#pragma unroll
        for (int j = 0; j < 2; ++j) {
            const int row = wn + j * 16 + ln;
            const int ch  = quad ^ ((row >> 1) & 3);
            b[j] = *(const short8*)&Bs[row * BK + ch * 8];
        }
#pragma unroll
        for (int i = 0; i < 4; ++i)
#pragma unroll
            for (int j = 0; j < 2; ++j)
                acc[i][j] = __builtin_amdgcn_mfma_f32_16x16x32_bf16(
                    a[i], b[j], acc[i][j], 0, 0, 0);
    }

#pragma unroll
    for (int j = 0; j < 2; ++j) {
        const int col = n0 + wn + j * 16 + ln;
        const float bv = bias[col];
#pragma unroll
        for (int i = 0; i < 4; ++i)
#pragma unroll
            for (int r2 = 0; r2 < 4; ++r2) {
                const int row = m0 + wm + i * 16 + quad * 4 + r2;
                C[(size_t)row * N + col] = acc[i][j][r2] + bv;
            }
    }
}

extern "C" void kernel_launch(void* const* d_in, const int* in_sizes, int n_in,
                              void* d_out, int out_size, void* d_ws, size_t ws_size,
                              hipStream_t stream)
{
    const float* x     = (const float*)d_in[0];
    const float* W_kqv = (const float*)d_in[1];
    const float* b_kqv = (const float*)d_in[2];
    const float* W_out = (const float*)d_in[3];
    const float* b_out = (const float*)d_in[4];
    float* out = (float*)d_out;

    char* w = (char*)d_ws;
    unsigned short* qbf   = (unsigned short*)w;  w += (size_t)BATCH * NHEAD * SEQ * HD * 2;
    unsigned short* kbf   = (unsigned short*)w;  w += (size_t)BATCH * NHEAD * SEQ * HD * 2;
    unsigned short* vtbf  = (unsigned short*)w;  w += (size_t)BATCH * NHEAD * HD * SEQ * 2;
    unsigned short* ctxbf = (unsigned short*)w;  w += (size_t)BATCH * SEQ * DIM * 2;
    unsigned short* xb    = (unsigned short*)w;  w += (size_t)BATCH * SEQ * DIM * 2;
    unsigned short* wkb   = (unsigned short*)w;  w += (size_t)QKV3 * DIM * 2;
    unsigned short* wob   = (unsigned short*)w;

    dim3 blk(256);

    conv_bf16<<<dim3(2048), blk, 0, stream>>>(x, W_kqv, W_out, xb, wkb, wob);

    gemm_qkv<<<dim3(768), blk, 0, stream>>>(xb, wkb, b_kqv, qbf, kbf, vtbf);

    // 512 blocks: bid = qt*32 + bh (bh low bits -> XCD-local KV)
    attn_flash_mfma<<<dim3(512), blk, 0, stream>>>(qbf, kbf, vtbf, ctxbf);

    gemm_out<<<dim3(512), blk, 0, stream>>>(ctxbf, wob, b_out, out);
}

// Round 9
// 191.068 us; speedup vs baseline: 1.0795x; 1.0744x over previous
//
#include <hip/hip_runtime.h>
#include <hip/hip_bf16.h>

#define DIM   1024
#define NHEAD 16
#define HD    64
#define SEQ   2048
#define BATCH 2
#define QKV3  3072

using short8 = __attribute__((ext_vector_type(8))) short;
using f32x4  = __attribute__((ext_vector_type(4))) float;

// fp32 -> bf16 (RNE) scalar
__device__ inline short f2bf(float f) {
    union { float f; unsigned u; } x; x.f = f;
    const unsigned r = (x.u + 0x7FFFu + ((x.u >> 16) & 1u)) >> 16;
    return (short)r;
}
// packed 2x fp32 -> bf16x2 (v_cvt_pk_bf16_f32)
__device__ inline unsigned pkbf(float a, float b) {
    union { __hip_bfloat162 h; unsigned u; } cv;
    cv.h = __float22bfloat162_rn(make_float2(a, b));
    return cv.u;
}

// async global->LDS DMA, 16 B per lane, LDS dest = wave-uniform base + lane*16.
__device__ __forceinline__ void g2l16(const void* gptr, void* ldsbase) {
    __builtin_amdgcn_global_load_lds(
        (const __attribute__((address_space(1))) unsigned int*)(unsigned long long)gptr,
        (__attribute__((address_space(3))) unsigned int*)(unsigned int)(unsigned long long)ldsbase,
        16, 0, 0);
}

// ======================================================================
// Convert x, W_kqv, W_out to bf16 (one pass).
// ======================================================================
__global__ __launch_bounds__(256)
void conv_bf16(const float* __restrict__ x, const float* __restrict__ wk,
               const float* __restrict__ wo,
               unsigned short* __restrict__ xb, unsigned short* __restrict__ wkb,
               unsigned short* __restrict__ wob)
{
    const int bid = blockIdx.x;
    const float* src; unsigned short* dst; size_t base;
    if (bid < 1024)      { src = x;  dst = xb;  base = (size_t)bid * 4096; }
    else if (bid < 1792) { src = wk; dst = wkb; base = (size_t)(bid - 1024) * 4096; }
    else                 { src = wo; dst = wob; base = (size_t)(bid - 1792) * 4096; }
    const size_t off = base + threadIdx.x * 16;
    const float4 f0 = *(const float4*)(src + off + 0);
    const float4 f1 = *(const float4*)(src + off + 4);
    const float4 f2 = *(const float4*)(src + off + 8);
    const float4 f3 = *(const float4*)(src + off + 12);
    uint4 o0, o1;
    o0.x = pkbf(f0.x, f0.y); o0.y = pkbf(f0.z, f0.w);
    o0.z = pkbf(f1.x, f1.y); o0.w = pkbf(f1.z, f1.w);
    o1.x = pkbf(f2.x, f2.y); o1.y = pkbf(f2.z, f2.w);
    o1.z = pkbf(f3.x, f3.y); o1.w = pkbf(f3.z, f3.w);
    *(uint4*)(dst + off + 0) = o0;
    *(uint4*)(dst + off + 8) = o1;
}

// ======================================================================
// QKV GEMM, bf16 MFMA, DMA-staged with PING-PONG LDS (attention-verified
// structure): DMA for tile k+1 issued into the idle buffer at the top of
// iter k, ONE barrier per iter (drain + swap ordering) -> DMA latency
// covered by the MFMA phase instead of exposed at a back-to-back barrier.
// LDS 32 KB -> 5 blocks/CU. Epilogue: q (x 0.125*log2e), k -> [b,h,s,d];
// v -> transposed [b,h,d,s].
// ======================================================================
__global__ __launch_bounds__(256)
void gemm_qkv(const unsigned short* __restrict__ A, const unsigned short* __restrict__ B,
              const float* __restrict__ bias,
              unsigned short* __restrict__ qbf, unsigned short* __restrict__ kbf,
              unsigned short* __restrict__ vtbf)
{
    constexpr int BK = 32, NIT = DIM / BK;
    const int K = DIM;
    __shared__ short As[2][128 * BK];   // 2 x 8 KB
    __shared__ short Bs[2][128 * BK];   // 2 x 8 KB

    const int tid  = threadIdx.x;
    const int lane = tid & 63;
    const int wave = tid >> 6;
    const int quad = lane >> 4;
    const int ln   = lane & 15;
    const int wm   = (wave & 1) * 64;
    const int wn   = (wave >> 1) * 64;

    const int bid = blockIdx.x;
    const int xcd = bid & 7;
    const int t   = bid >> 3;
    const int m0  = (xcd * 4 + (t & 3)) * 128;
    const int n0  = (t >> 2) * 128;

    int srow[2], sg[2];
#pragma unroll
    for (int i = 0; i < 2; ++i) {
        const int c  = wave * 128 + i * 64 + lane;
        srow[i] = c >> 2;
        sg[i]   = (c & 3) ^ ((srow[i] >> 1) & 3);
    }

    f32x4 acc[4][4];
#pragma unroll
    for (int i = 0; i < 4; ++i)
#pragma unroll
        for (int j = 0; j < 4; ++j) acc[i][j] = (f32x4){0.f, 0.f, 0.f, 0.f};

    // prologue: DMA tile 0 -> buffer 0
#pragma unroll
    for (int i = 0; i < 2; ++i) {
        const int cb = wave * 128 + i * 64;
        g2l16(A + (size_t)(m0 + srow[i]) * K + sg[i] * 8, &As[0][cb * 8]);
        g2l16(B + (size_t)(n0 + srow[i]) * K + sg[i] * 8, &Bs[0][cb * 8]);
    }
    __syncthreads();

    for (int kt = 0; kt < NIT; ++kt) {
        const int p = kt & 1;
        if (kt + 1 < NIT) {
            const int kn = (kt + 1) * BK;
#pragma unroll
            for (int i = 0; i < 2; ++i) {
                const int cb = wave * 128 + i * 64;
                g2l16(A + (size_t)(m0 + srow[i]) * K + kn + sg[i] * 8, &As[1 - p][cb * 8]);
                g2l16(B + (size_t)(n0 + srow[i]) * K + kn + sg[i] * 8, &Bs[1 - p][cb * 8]);
            }
        }

        short8 a[4], b[4];
#pragma unroll
        for (int i = 0; i < 4; ++i) {
            const int row = wm + i * 16 + ln;
            const int ch  = quad ^ ((row >> 1) & 3);
            a[i] = *(const short8*)&As[p][row * BK + ch * 8];
        }
#pragma unroll
        for (int j = 0; j < 4; ++j) {
            const int row = wn + j * 16 + ln;
            const int ch  = quad ^ ((row >> 1) & 3);
            b[j] = *(const short8*)&Bs[p][row * BK + ch * 8];
        }
#pragma unroll
        for (int i = 0; i < 4; ++i)
#pragma unroll
            for (int j = 0; j < 4; ++j)
                acc[i][j] = __builtin_amdgcn_mfma_f32_16x16x32_bf16(
                    a[i], b[j], acc[i][j], 0, 0, 0);
        __syncthreads();   // single barrier: drains next-tile DMA, orders swap
    }

#pragma unroll
    for (int j = 0; j < 4; ++j) {
        const int col = n0 + wn + j * 16 + ln;
        const int sel = col >> 10;
        const int c   = col & 1023;
        const int hh  = c >> 6;
        const int dd  = c & 63;
        const float bv = bias[col];
        if (sel < 2) {
            unsigned short* dst = (sel == 0) ? qbf : kbf;
            // 0.125 * log2(e): softmax becomes a bare exp2
            const float qs = (sel == 0) ? 0.18033688f : 1.0f;
#pragma unroll
            for (int i = 0; i < 4; ++i)
#pragma unroll
                for (int r2 = 0; r2 < 4; ++r2) {
                    const int row = m0 + wm + i * 16 + quad * 4 + r2;
                    const int bb = row >> 11, ss = row & 2047;
                    dst[((size_t)(bb * NHEAD + hh) * SEQ + ss) * HD + dd] =
                        (unsigned short)f2bf((acc[i][j][r2] + bv) * qs);
                }
        } else {
            const int row0 = m0 + wm + quad * 4;
            const int bb = row0 >> 11;
            const size_t vbase = ((size_t)(bb * NHEAD + hh) * HD + dd) * SEQ;
#pragma unroll
            for (int i = 0; i < 4; ++i) {
                const int ss0 = (row0 & 2047) + i * 16;
                uint2 pk;
                pk.x = pkbf(acc[i][j][0] + bv, acc[i][j][1] + bv);
                pk.y = pkbf(acc[i][j][2] + bv, acc[i][j][3] + bv);
                *(uint2*)&vtbf[vbase + ss0] = pk;
            }
        }
    }
}

// ======================================================================
// Flash attention (unchanged from round 8): bf16 MFMA, no-max exp2
// softmax, BQ=128, ping-pong DMA K/V staging, 1 barrier/iter,
// XCD-local KV (FETCH 12.3 MB measured), l = P @ ones via MFMA.
// ======================================================================
__global__ __launch_bounds__(256)
void attn_flash_mfma(const unsigned short* __restrict__ qbf,
                     const unsigned short* __restrict__ kbf,
                     const unsigned short* __restrict__ vtbf,
                     unsigned short* __restrict__ ctxbf)
{
    constexpr int LDP = 72;
    __shared__ short Ks[2][64 * 64];
    __shared__ short Vt[2][64 * 64];
    __shared__ short Ps[128 * LDP];

    const int tid  = threadIdx.x;
    const int lane = tid & 63;
    const int wave = tid >> 6;
    const int quad = lane >> 4;
    const int ln   = lane & 15;

    const int bid = blockIdx.x;          // qt*32 + bh
    const int bh  = bid & 31;
    const int qt  = bid >> 5;
    const int q0  = qt * 128;
    const int b   = bh >> 4;
    const int h   = bh & 15;

    const size_t sbase = (size_t)bh * SEQ * HD;
    const size_t vbase = (size_t)bh * HD * SEQ;

    int srw[2], scg[2];
#pragma unroll
    for (int it = 0; it < 2; ++it) {
        const int ch = tid + it * 256;
        srw[it] = ch >> 3;
        scg[it] = (ch & 7) ^ (srw[it] & 7);
    }

#pragma unroll
    for (int it = 0; it < 4; ++it) {
        const int ch = tid + it * 256;
        const int r  = ch >> 3;
        const int cc = ch & 7;
        *(short8*)&Ps[r * LDP + cc * 8] =
            *(const short8*)&qbf[sbase + (size_t)(q0 + r) * HD + cc * 8];
    }
#pragma unroll
    for (int it = 0; it < 2; ++it) {
        const int cb = tid + it * 256;
        g2l16(kbf + sbase + (size_t)srw[it] * HD + scg[it] * 8, &Ks[0][cb * 8]);
        g2l16(vtbf + vbase + (size_t)srw[it] * SEQ + scg[it] * 8, &Vt[0][cb * 8]);
    }
    __syncthreads();

    short8 qf[2][2];
#pragma unroll
    for (int sm = 0; sm < 2; ++sm)
#pragma unroll
        for (int kc = 0; kc < 2; ++kc)
            qf[sm][kc] = *(const short8*)&Ps[(wave * 32 + sm * 16 + ln) * LDP + kc * 32 + quad * 8];

    f32x4 O[2][4];
#pragma unroll
    for (int sm = 0; sm < 2; ++sm)
#pragma unroll
        for (int dj = 0; dj < 4; ++dj) O[sm][dj] = (f32x4){0.f, 0.f, 0.f, 0.f};
    f32x4 lacc[2];
    lacc[0] = (f32x4){0.f, 0.f, 0.f, 0.f};
    lacc[1] = (f32x4){0.f, 0.f, 0.f, 0.f};

    short8 vone;
#pragma unroll
    for (int t = 0; t < 8; ++t) vone[t] = (short)0x3F80;

    for (int kt = 0; kt < SEQ / 64; ++kt) {
        const int p = kt & 1;
        if (kt + 1 < SEQ / 64) {
            const int k0n = (kt + 1) * 64;
#pragma unroll
            for (int it = 0; it < 2; ++it) {
                const int cb = tid + it * 256;
                g2l16(kbf + sbase + (size_t)(k0n + srw[it]) * HD + scg[it] * 8,
                      &Ks[1 - p][cb * 8]);
                g2l16(vtbf + vbase + (size_t)srw[it] * SEQ + k0n + scg[it] * 8,
                      &Vt[1 - p][cb * 8]);
            }
        }

        f32x4 st[2][4];
#pragma unroll
        for (int j = 0; j < 4; ++j) {
            const int row = j * 16 + ln;
            const int c0 = quad ^ (row & 7);
            const int c1 = (4 + quad) ^ (row & 7);
            const short8 kf0 = *(const short8*)&Ks[p][row * 64 + c0 * 8];
            const short8 kf1 = *(const short8*)&Ks[p][row * 64 + c1 * 8];
#pragma unroll
            for (int sm = 0; sm < 2; ++sm) {
                f32x4 tt = __builtin_amdgcn_mfma_f32_16x16x32_bf16(
                    kf0, qf[sm][0], (f32x4){0.f, 0.f, 0.f, 0.f}, 0, 0, 0);
                st[sm][j] = __builtin_amdgcn_mfma_f32_16x16x32_bf16(
                    kf1, qf[sm][1], tt, 0, 0, 0);
            }
        }

#pragma unroll
        for (int sm = 0; sm < 2; ++sm)
#pragma unroll
            for (int j = 0; j < 4; ++j) {
                const float p0 = __builtin_amdgcn_exp2f(st[sm][j][0]);
                const float p1 = __builtin_amdgcn_exp2f(st[sm][j][1]);
                const float p2 = __builtin_amdgcn_exp2f(st[sm][j][2]);
                const float p3 = __builtin_amdgcn_exp2f(st[sm][j][3]);
                uint2 pk;
                pk.x = pkbf(p0, p1);
                pk.y = pkbf(p2, p3);
                *(uint2*)&Ps[(wave * 32 + sm * 16 + ln) * LDP + j * 16 + quad * 4] = pk;
            }

#pragma unroll
        for (int kc = 0; kc < 2; ++kc) {
            const short8 pf0 = *(const short8*)&Ps[(wave * 32 + ln) * LDP + kc * 32 + quad * 8];
            const short8 pf1 = *(const short8*)&Ps[(wave * 32 + 16 + ln) * LDP + kc * 32 + quad * 8];
            lacc[0] = __builtin_amdgcn_mfma_f32_16x16x32_bf16(pf0, vone, lacc[0], 0, 0, 0);
            lacc[1] = __builtin_amdgcn_mfma_f32_16x16x32_bf16(pf1, vone, lacc[1], 0, 0, 0);
#pragma unroll
            for (int dj = 0; dj < 4; ++dj) {
                const int row = dj * 16 + ln;
                const int cg  = (kc * 4 + quad) ^ (row & 7);
                const short8 vf = *(const short8*)&Vt[p][row * 64 + cg * 8];
                O[0][dj] = __builtin_amdgcn_mfma_f32_16x16x32_bf16(pf0, vf, O[0][dj], 0, 0, 0);
                O[1][dj] = __builtin_amdgcn_mfma_f32_16x16x32_bf16(pf1, vf, O[1][dj], 0, 0, 0);
            }
        }
        __syncthreads();
    }

#pragma unroll
    for (int sm = 0; sm < 2; ++sm)
#pragma unroll
        for (int r2 = 0; r2 < 4; ++r2) {
            const float inv = 1.0f / lacc[sm][r2];
            const int row = b * SEQ + q0 + wave * 32 + sm * 16 + quad * 4 + r2;
#pragma unroll
            for (int dj = 0; dj < 4; ++dj)
                ctxbf[(size_t)row * DIM + h * HD + dj * 16 + ln] =
                    (unsigned short)f2bf(O[sm][dj][r2] * inv);
        }
}

// ======================================================================
// Out-proj GEMM, ping-pong DMA pipeline (same structure as gemm_qkv).
// BM=128 x BN=64 -> 512 blocks. LDS 24 KB -> 6 blocks/CU.
// ======================================================================
__global__ __launch_bounds__(256)
void gemm_out(const unsigned short* __restrict__ A, const unsigned short* __restrict__ B,
              const float* __restrict__ bias, float* __restrict__ C)
{
    constexpr int BK = 32, NIT = DIM / BK;
    const int K = DIM, N = DIM;
    __shared__ short As[2][128 * BK];   // 2 x 8 KB
    __shared__ short Bs[2][64 * BK];    // 2 x 4 KB

    const int tid  = threadIdx.x;
    const int lane = tid & 63;
    const int wave = tid >> 6;
    const int quad = lane >> 4;
    const int ln   = lane & 15;
    const int wm   = (wave & 1) * 64;
    const int wn   = (wave >> 1) * 32;

    const int bid = blockIdx.x;
    const int xcd = bid & 7;
    const int t   = bid >> 3;
    const int m0  = (xcd * 4 + (t & 3)) * 128;
    const int n0  = (t >> 2) * 64;

    int srow[2], sg[2];
#pragma unroll
    for (int i = 0; i < 2; ++i) {
        const int c  = wave * 128 + i * 64 + lane;
        srow[i] = c >> 2;
        sg[i]   = (c & 3) ^ ((srow[i] >> 1) & 3);
    }
    const int cB  = wave * 64 + lane;
    const int brow = cB >> 2;
    const int bg   = (cB & 3) ^ ((brow >> 1) & 3);

    f32x4 acc[4][2];
#pragma unroll
    for (int i = 0; i < 4; ++i)
#pragma unroll
        for (int j = 0; j < 2; ++j) acc[i][j] = (f32x4){0.f, 0.f, 0.f, 0.f};

    // prologue: DMA tile 0 -> buffer 0
#pragma unroll
    for (int i = 0; i < 2; ++i)
        g2l16(A + (size_t)(m0 + srow[i]) * K + sg[i] * 8,
              &As[0][(wave * 128 + i * 64) * 8]);
    g2l16(B + (size_t)(n0 + brow) * K + bg * 8, &Bs[0][(wave * 64) * 8]);
    __syncthreads();

    for (int kt = 0; kt < NIT; ++kt) {
        const int p = kt & 1;
        if (kt + 1 < NIT) {
            const int kn = (kt + 1) * BK;
#pragma unroll
            for (int i = 0; i < 2; ++i)
                g2l16(A + (size_t)(m0 + srow[i]) * K + kn + sg[i] * 8,
                      &As[1 - p][(wave * 128 + i * 64) * 8]);
            g2l16(B + (size_t)(n0 + brow) * K + kn + bg * 8, &Bs[1 - p][(wave * 64) * 8]);
        }

        short8 a[4], b[2];
#pragma unroll
        for (int i = 0; i < 4; ++i) {
            const int row = wm + i * 16 + ln;
            const int ch  = quad ^ ((row >> 1) & 3);
            a[i] = *(const short8*)&As[p][row * BK + ch * 8];
        }
#pragma unroll
        for (int j = 0; j < 2; ++j) {
            const int row = wn + j * 16 + ln;
            const int ch  = quad ^ ((row >> 1) & 3);
            b[j] = *(const short8*)&Bs[p][row * BK + ch * 8];
        }
#pragma unroll
        for (int i = 0; i < 4; ++i)
#pragma unroll
            for (int j = 0; j < 2; ++j)
                acc[i][j] = __builtin_amdgcn_mfma_f32_16x16x32_bf16(
                    a[i], b[j], acc[i][j], 0, 0, 0);
        __syncthreads();
    }

#pragma unroll
    for (int j = 0; j < 2; ++j) {
        const int col = n0 + wn + j * 16 + ln;
        const float bv = bias[col];
#pragma unroll
        for (int i = 0; i < 4; ++i)
#pragma unroll
            for (int r2 = 0; r2 < 4; ++r2) {
                const int row = m0 + wm + i * 16 + quad * 4 + r2;
                C[(size_t)row * N + col] = acc[i][j][r2] + bv;
            }
    }
}

extern "C" void kernel_launch(void* const* d_in, const int* in_sizes, int n_in,
                              void* d_out, int out_size, void* d_ws, size_t ws_size,
                              hipStream_t stream)
{
    const float* x     = (const float*)d_in[0];
    const float* W_kqv = (const float*)d_in[1];
    const float* b_kqv = (const float*)d_in[2];
    const float* W_out = (const float*)d_in[3];
    const float* b_out = (const float*)d_in[4];
    float* out = (float*)d_out;

    char* w = (char*)d_ws;
    unsigned short* qbf   = (unsigned short*)w;  w += (size_t)BATCH * NHEAD * SEQ * HD * 2;
    unsigned short* kbf   = (unsigned short*)w;  w += (size_t)BATCH * NHEAD * SEQ * HD * 2;
    unsigned short* vtbf  = (unsigned short*)w;  w += (size_t)BATCH * NHEAD * HD * SEQ * 2;
    unsigned short* ctxbf = (unsigned short*)w;  w += (size_t)BATCH * SEQ * DIM * 2;
    unsigned short* xb    = (unsigned short*)w;  w += (size_t)BATCH * SEQ * DIM * 2;
    unsigned short* wkb   = (unsigned short*)w;  w += (size_t)QKV3 * DIM * 2;
    unsigned short* wob   = (unsigned short*)w;

    dim3 blk(256);

    conv_bf16<<<dim3(2048), blk, 0, stream>>>(x, W_kqv, W_out, xb, wkb, wob);

    gemm_qkv<<<dim3(768), blk, 0, stream>>>(xb, wkb, b_kqv, qbf, kbf, vtbf);

    attn_flash_mfma<<<dim3(512), blk, 0, stream>>>(qbf, kbf, vtbf, ctxbf);

    gemm_out<<<dim3(512), blk, 0, stream>>>(ctxbf, wob, b_out, out);
}